// Round 8
// baseline (752.742 us; speedup 1.0000x reference)
//
#include <hip/hip_runtime.h>
#include <stdint.h>
#include <math.h>

#define NEG 0.2f
#define TINYF 1.1754943508222875e-38f

// ---------------- Threefry-2x32-20 (matches JAX) ----------------
__host__ __device__ inline void threefry2x32(uint32_t k0, uint32_t k1,
                                             uint32_t x0, uint32_t x1,
                                             uint32_t* o0, uint32_t* o1) {
  uint32_t ks0 = k0, ks1 = k1, ks2 = k0 ^ k1 ^ 0x1BD11BDAu;
  x0 += ks0; x1 += ks1;
#define RR(r) { x0 += x1; x1 = (x1 << (r)) | (x1 >> (32 - (r))); x1 ^= x0; }
  RR(13) RR(15) RR(26) RR(6)
  x0 += ks1; x1 += ks2 + 1u;
  RR(17) RR(29) RR(16) RR(24)
  x0 += ks2; x1 += ks0 + 2u;
  RR(13) RR(15) RR(26) RR(6)
  x0 += ks0; x1 += ks1 + 3u;
  RR(17) RR(29) RR(16) RR(24)
  x0 += ks1; x1 += ks2 + 4u;
  RR(13) RR(15) RR(26) RR(6)
  x0 += ks2; x1 += ks0 + 5u;
#undef RR
  *o0 = x0; *o1 = x1;
}

// jax_threefry_partitionable=True random_bits, bit_width=32:
//   bits[i] = o0 ^ o1 of TF(key, (0, i))   [verified exact: R3-R7 pass]
__device__ inline float gumbel_part(uint32_t ka, uint32_t kb, uint32_t i) {
  uint32_t o0, o1;
  threefry2x32(ka, kb, 0u, i, &o0, &o1);
  uint32_t bits = o0 ^ o1;
  float f = __uint_as_float((bits >> 9) | 0x3f800000u) - 1.0f;
  float u = fmaxf(TINYF, f + TINYF);
  return -logf(-logf(u));
}

// ---------------- CSR build ----------------
__global__ void count_kernel(const int* __restrict__ ei, int E, int* __restrict__ counts) {
  int e = blockIdx.x * blockDim.x + threadIdx.x;
  if (e < E) atomicAdd(&counts[ei[E + e]], 1);
}

__global__ __launch_bounds__(1024) void scan_kernel(const int* __restrict__ counts,
    int* __restrict__ row_start, int* __restrict__ cursor, int N, int E) {
  __shared__ int wsum[16];
  __shared__ int base_s;
  int tid = threadIdx.x;
  int lane = tid & 63, wv = tid >> 6;
  if (tid == 0) base_s = 0;
  __syncthreads();
  for (int chunk = 0; chunk < N; chunk += 1024) {
    int i = chunk + tid;
    int v = (i < N) ? counts[i] : 0;
    int incl = v;
#pragma unroll
    for (int off = 1; off < 64; off <<= 1) {
      int t = __shfl_up(incl, off);
      if (lane >= off) incl += t;
    }
    if (lane == 63) wsum[wv] = incl;
    __syncthreads();
    if (wv == 0) {
      int x = (lane < 16) ? wsum[lane] : 0;
#pragma unroll
      for (int off = 1; off < 16; off <<= 1) {
        int t = __shfl_up(x, off);
        if (lane >= off) x += t;
      }
      if (lane < 16) wsum[lane] = x;
    }
    __syncthreads();
    int waveoff = (wv == 0) ? 0 : wsum[wv - 1];
    int base = base_s;
    int excl = base + waveoff + incl - v;
    if (i < N) { row_start[i] = excl; cursor[i] = excl; }
    __syncthreads();
    if (tid == 1023) base_s = base + wsum[15];
    __syncthreads();
  }
  if (tid == 0) row_start[N] = base_s;
}

// scatter: src_csr + ea permuted into CSR order (streamed reads downstream)
__global__ void scatter_kernel(const int* __restrict__ ei, const float* __restrict__ ea,
                               int E, int* __restrict__ cursor,
                               int* __restrict__ src_csr, float* __restrict__ ea_csr) {
  int e = blockIdx.x * blockDim.x + threadIdx.x;
  if (e < E) {
    int d = ei[E + e];
    int p = atomicAdd(&cursor[d], 1);
    src_csr[p] = ei[e];
    const float4* s4 = (const float4*)&ea[(size_t)e * 16];
    float4* d4 = (float4*)&ea_csr[(size_t)p * 16];
    float4 t0 = s4[0], t1 = s4[1], t2 = s4[2], t3 = s4[3];
    d4[0] = t0; d4[1] = t1; d4[2] = t2; d4[3] = t3;
  }
}

// ---------------- h = X @ W (128x128) + b ----------------
__global__ __launch_bounds__(256) void gemm128_kernel(const float* __restrict__ X,
    const float* __restrict__ W, const float* __restrict__ bias,
    float* __restrict__ out, int M) {
  __shared__ float xs[128][33];
  int row0 = blockIdx.x * 32;
  int tid = threadIdx.x;
  for (int idx = tid; idx < 32 * 128; idx += 256) {
    int r = idx >> 7;
    int k = idx & 127;
    int row = row0 + r;
    xs[k][r] = (row < M) ? X[(size_t)row * 128 + k] : 0.0f;
  }
  __syncthreads();
  int tc = tid & 31, tr = tid >> 5;
  int c0 = tc * 4, r0 = tr * 4;
  float acc[4][4] = {};
#pragma unroll 4
  for (int k = 0; k < 128; k++) {
    float4 w = *(const float4*)&W[k * 128 + c0];
    float x0 = xs[k][r0], x1 = xs[k][r0 + 1], x2 = xs[k][r0 + 2], x3 = xs[k][r0 + 3];
    acc[0][0] += x0 * w.x; acc[0][1] += x0 * w.y; acc[0][2] += x0 * w.z; acc[0][3] += x0 * w.w;
    acc[1][0] += x1 * w.x; acc[1][1] += x1 * w.y; acc[1][2] += x1 * w.z; acc[1][3] += x1 * w.w;
    acc[2][0] += x2 * w.x; acc[2][1] += x2 * w.y; acc[2][2] += x2 * w.z; acc[2][3] += x2 * w.w;
    acc[3][0] += x3 * w.x; acc[3][1] += x3 * w.y; acc[3][2] += x3 * w.z; acc[3][3] += x3 * w.w;
  }
  float4 b4 = *(const float4*)&bias[c0];
  for (int r = 0; r < 4; r++) {
    int row = row0 + r0 + r;
    if (row < M) {
      float4 o;
      o.x = acc[r][0] + b4.x; o.y = acc[r][1] + b4.y;
      o.z = acc[r][2] + b4.z; o.w = acc[r][3] + b4.w;
      *(float4*)&out[(size_t)row * 128 + c0] = o;
    }
  }
}

// ---------------- h3 = latent @ Wl3 (128x32) + b ----------------
__global__ __launch_bounds__(256) void gemm32_kernel(const float* __restrict__ X,
    const float* __restrict__ W, const float* __restrict__ bias,
    float* __restrict__ out, int M) {
  int t = blockIdx.x * 256 + threadIdx.x;
  int node = t >> 5, c = t & 31;
  if (node >= M) return;
  const float4* xp = (const float4*)&X[(size_t)node * 128];
  float acc = 0.f;
#pragma unroll
  for (int q = 0; q < 32; q++) {
    float4 x4 = xp[q];
    acc += x4.x * W[(q * 4 + 0) * 32 + c] + x4.y * W[(q * 4 + 1) * 32 + c]
         + x4.z * W[(q * 4 + 2) * 32 + c] + x4.w * W[(q * 4 + 3) * 32 + c];
  }
  out[(size_t)node * 32 + c] = acc + bias[c];
}

// ---------------- h2 = latent @ Wl2 (128x1) + b ----------------
__global__ __launch_bounds__(256) void gemv_kernel(const float* __restrict__ X,
    const float* __restrict__ w, const float* __restrict__ b0,
    float* __restrict__ out, int M) {
  int wv = (blockIdx.x * 256 + threadIdx.x) >> 6;
  int lane = threadIdx.x & 63;
  if (wv >= M) return;
  float2 xv = *(const float2*)&X[(size_t)wv * 128 + lane * 2];
  float2 wvv = *(const float2*)&w[lane * 2];
  float v = xv.x * wvv.x + xv.y * wvv.y;
#pragma unroll
  for (int off = 32; off; off >>= 1) v += __shfl_xor(v, off);
  if (lane == 0) out[wv] = v + b0[0];
}

// ---------------- layer-1 fused (QUARTER-wave per node: 16 lanes x 8 dims) ----------------
__global__ __launch_bounds__(256) void fused1_kernel(const float* __restrict__ h,
    const int* __restrict__ src_csr, const int* __restrict__ row_start,
    const float* __restrict__ ea_csr,
    const float* __restrict__ We, const float* __restrict__ att,
    const float* __restrict__ bias, float* __restrict__ out, int N) {
  __shared__ float WeS[2048];
  int tid = threadIdx.x;
  for (int i = tid; i < 2048; i += 256) WeS[i] = We[i];
  __syncthreads();
  int node = (blockIdx.x * 256 + tid) >> 4;   // quarter-wave = one node
  int l16 = tid & 15;
  if (node >= N) return;
  int c8 = l16 * 8;
  float4 at0 = *(const float4*)&att[c8];
  float4 at1 = *(const float4*)&att[c8 + 4];
  float4 bb0 = *(const float4*)&bias[c8];
  float4 bb1 = *(const float4*)&bias[c8 + 4];
  int start = row_start[node];
  int deg = row_start[node + 1] - start;
  float* op = &out[(size_t)node * 128 + c8];
  if (deg == 0) {
    *(float4*)op = bb0;
    *(float4*)(op + 4) = bb1;
    return;
  }
  const float4* hp0 = (const float4*)&h[(size_t)node * 128 + c8];
  float4 hi0 = hp0[0], hi1 = hp0[1];
  int s_l = (l16 < deg) ? src_csr[start + l16] : 0;
  int dcap = deg < 16 ? deg : 16;
  const float4* eap = (const float4*)&ea_csr[(size_t)start * 16];
  float m = -INFINITY, l = 0.f;
  float4 acc0 = make_float4(0.f, 0.f, 0.f, 0.f);
  float4 acc1 = make_float4(0.f, 0.f, 0.f, 0.f);
  for (int j = 0; j < deg; j++) {
    int s = (j < dcap) ? __shfl(s_l, j, 16) : src_csr[start + j];
    const float4* hjp = (const float4*)&h[(size_t)s * 128 + c8];
    float4 hj0 = hjp[0], hj1 = hjp[1];
    float4 v0, v1;
    v0.x = hi0.x + hj0.x; v0.y = hi0.y + hj0.y; v0.z = hi0.z + hj0.z; v0.w = hi0.w + hj0.w;
    v1.x = hi1.x + hj1.x; v1.y = hi1.y + hj1.y; v1.z = hi1.z + hj1.z; v1.w = hi1.w + hj1.w;
#pragma unroll
    for (int q = 0; q < 4; q++) {
      float4 aq = eap[(size_t)j * 4 + q];
#pragma unroll
      for (int r = 0; r < 4; r++) {
        int k = 4 * q + r;
        float a = (r == 0) ? aq.x : (r == 1) ? aq.y : (r == 2) ? aq.z : aq.w;
        float4 wa = *(const float4*)&WeS[k * 128 + c8];
        float4 wb = *(const float4*)&WeS[k * 128 + c8 + 4];
        v0.x += a * wa.x; v0.y += a * wa.y; v0.z += a * wa.z; v0.w += a * wa.w;
        v1.x += a * wb.x; v1.y += a * wb.y; v1.z += a * wb.z; v1.w += a * wb.w;
      }
    }
    v0.x = v0.x >= 0.f ? v0.x : NEG * v0.x;
    v0.y = v0.y >= 0.f ? v0.y : NEG * v0.y;
    v0.z = v0.z >= 0.f ? v0.z : NEG * v0.z;
    v0.w = v0.w >= 0.f ? v0.w : NEG * v0.w;
    v1.x = v1.x >= 0.f ? v1.x : NEG * v1.x;
    v1.y = v1.y >= 0.f ? v1.y : NEG * v1.y;
    v1.z = v1.z >= 0.f ? v1.z : NEG * v1.z;
    v1.w = v1.w >= 0.f ? v1.w : NEG * v1.w;
    float sc = v0.x * at0.x + v0.y * at0.y + v0.z * at0.z + v0.w * at0.w
             + v1.x * at1.x + v1.y * at1.y + v1.z * at1.z + v1.w * at1.w;
#pragma unroll
    for (int off = 8; off; off >>= 1) sc += __shfl_xor(sc, off);
    float mn = fmaxf(m, sc);
    float scale = __expf(m - mn);   // first edge: exp(-inf)=0
    float w = __expf(sc - mn);
    l = l * scale + w;
    acc0.x = acc0.x * scale + w * hj0.x;
    acc0.y = acc0.y * scale + w * hj0.y;
    acc0.z = acc0.z * scale + w * hj0.z;
    acc0.w = acc0.w * scale + w * hj0.w;
    acc1.x = acc1.x * scale + w * hj1.x;
    acc1.y = acc1.y * scale + w * hj1.y;
    acc1.z = acc1.z * scale + w * hj1.z;
    acc1.w = acc1.w * scale + w * hj1.w;
    m = mn;
  }
  float inv = 1.0f / (l + 1e-16f);
  float4 o0, o1;
  o0.x = acc0.x * inv + bb0.x; o0.y = acc0.y * inv + bb0.y;
  o0.z = acc0.z * inv + bb0.z; o0.w = acc0.w * inv + bb0.w;
  o1.x = acc1.x * inv + bb1.x; o1.y = acc1.y * inv + bb1.y;
  o1.z = acc1.z * inv + bb1.z; o1.w = acc1.w * inv + bb1.w;
  *(float4*)op = o0;
  *(float4*)(op + 4) = o1;
}

// ---------------- layers 2+3 fused (wave/node, QUARTER-wave per edge: 4 in flight) ----------------
__global__ __launch_bounds__(256) void fused23_kernel(
    const float* __restrict__ h3, const float* __restrict__ h2,
    const int* __restrict__ src_csr, const int* __restrict__ row_start,
    const float* __restrict__ ea_csr,
    const float* __restrict__ We3, const float* __restrict__ att3,
    const float* __restrict__ bias3, const float* __restrict__ We2,
    const float* __restrict__ att2, const float* __restrict__ bias2,
    float* __restrict__ out3, float* __restrict__ logits, int N) {
  int tid = threadIdx.x;
  int wv = (blockIdx.x * 256 + tid) >> 6;
  int lane = tid & 63;
  if (wv >= N) return;
  int q4 = lane >> 4;        // quarter index 0..3
  int l16 = lane & 15;
  int c2 = l16 * 2;          // 2 dims per lane (32 dims / 16 lanes)
  // register weights: We3 2-col slice (32 VGPR), We2 uniform (SGPRs)
  float2 we3[16];
#pragma unroll
  for (int k = 0; k < 16; k++) we3[k] = *(const float2*)&We3[k * 32 + c2];
  float we2[16];
#pragma unroll
  for (int k = 0; k < 16; k++) we2[k] = We2[k];
  float2 at3 = *(const float2*)&att3[c2];
  float a2s = att2[0];
  float2 bi3 = *(const float2*)&bias3[c2];
  int start = row_start[wv];
  int deg = row_start[wv + 1] - start;
  if (deg == 0) {
    if (lane < 16) *(float2*)&out3[(size_t)wv * 32 + c2] = bi3;
    if (lane == 0) logits[wv] = bias2[0];
    return;
  }
  float2 hi3 = *(const float2*)&h3[(size_t)wv * 32 + c2];
  float hi2 = h2[wv];
  int s_l = (lane < deg) ? src_csr[start + lane] : 0;
  int dcap = deg < 64 ? deg : 64;
  const float4* eap = (const float4*)&ea_csr[(size_t)start * 16];
  // per-quarter online state
  float m3 = -INFINITY, l3 = 0.f; float2 a3 = make_float2(0.f, 0.f);
  float m2 = -INFINITY, l2 = 0.f; float a2 = 0.f;
  for (int j = q4; j < deg; j += 4) {
    int s = (j < dcap) ? __shfl(s_l, j) : src_csr[start + j];
    float2 hj3 = *(const float2*)&h3[(size_t)s * 32 + c2];
    float h2s = h2[s];
    float4 c0 = eap[(size_t)j * 4 + 0];
    float4 c1 = eap[(size_t)j * 4 + 1];
    float4 cc2 = eap[(size_t)j * 4 + 2];
    float4 c3 = eap[(size_t)j * 4 + 3];
    float vx = hi3.x + hj3.x, vy = hi3.y + hj3.y;
    vx += c0.x * we3[0].x + c0.y * we3[1].x + c0.z * we3[2].x + c0.w * we3[3].x;
    vy += c0.x * we3[0].y + c0.y * we3[1].y + c0.z * we3[2].y + c0.w * we3[3].y;
    vx += c1.x * we3[4].x + c1.y * we3[5].x + c1.z * we3[6].x + c1.w * we3[7].x;
    vy += c1.x * we3[4].y + c1.y * we3[5].y + c1.z * we3[6].y + c1.w * we3[7].y;
    vx += cc2.x * we3[8].x + cc2.y * we3[9].x + cc2.z * we3[10].x + cc2.w * we3[11].x;
    vy += cc2.x * we3[8].y + cc2.y * we3[9].y + cc2.z * we3[10].y + cc2.w * we3[11].y;
    vx += c3.x * we3[12].x + c3.y * we3[13].x + c3.z * we3[14].x + c3.w * we3[15].x;
    vy += c3.x * we3[12].y + c3.y * we3[13].y + c3.z * we3[14].y + c3.w * we3[15].y;
    vx = vx >= 0.f ? vx : NEG * vx;
    vy = vy >= 0.f ? vy : NEG * vy;
    float t3 = vx * at3.x + vy * at3.y;
#pragma unroll
    for (int off = 8; off; off >>= 1) t3 += __shfl_xor(t3, off);
    float v2 = hi2 + h2s;
    v2 += c0.x * we2[0]  + c0.y * we2[1]  + c0.z * we2[2]  + c0.w * we2[3];
    v2 += c1.x * we2[4]  + c1.y * we2[5]  + c1.z * we2[6]  + c1.w * we2[7];
    v2 += cc2.x * we2[8] + cc2.y * we2[9] + cc2.z * we2[10] + cc2.w * we2[11];
    v2 += c3.x * we2[12] + c3.y * we2[13] + c3.z * we2[14] + c3.w * we2[15];
    v2 = v2 >= 0.f ? v2 : NEG * v2;
    float t2 = v2 * a2s;
    float mn3 = fmaxf(m3, t3);
    float sc3 = __expf(m3 - mn3);
    float w3 = __expf(t3 - mn3);
    l3 = l3 * sc3 + w3;
    a3.x = a3.x * sc3 + w3 * hj3.x;
    a3.y = a3.y * sc3 + w3 * hj3.y;
    m3 = mn3;
    float mn2 = fmaxf(m2, t2);
    float sc2 = __expf(m2 - mn2);
    float w2 = __expf(t2 - mn2);
    l2 = l2 * sc2 + w2;
    a2 = a2 * sc2 + w2 * h2s;
    m2 = mn2;
  }
  // merge 4 quarter states (xor 16 then 32); quarter 0 has >=1 edge
#pragma unroll
  for (int off = 16; off <= 32; off <<= 1) {
    float m3o = __shfl_xor(m3, off), l3o = __shfl_xor(l3, off);
    float ax = __shfl_xor(a3.x, off), ay = __shfl_xor(a3.y, off);
    float M3 = fmaxf(m3, m3o);
    float sA = (m3 == -INFINITY) ? 0.f : __expf(m3 - M3);
    float sB = (m3o == -INFINITY) ? 0.f : __expf(m3o - M3);
    l3 = l3 * sA + l3o * sB;
    a3.x = a3.x * sA + ax * sB;
    a3.y = a3.y * sA + ay * sB;
    m3 = M3;
    float m2o = __shfl_xor(m2, off), l2o = __shfl_xor(l2, off);
    float az = __shfl_xor(a2, off);
    float M2 = fmaxf(m2, m2o);
    float tA = (m2 == -INFINITY) ? 0.f : __expf(m2 - M2);
    float tB = (m2o == -INFINITY) ? 0.f : __expf(m2o - M2);
    l2 = l2 * tA + l2o * tB;
    a2 = a2 * tA + az * tB;
    m2 = M2;
  }
  if (lane < 16) {
    float2 o;
    o.x = a3.x / (l3 + 1e-16f) + bi3.x;
    o.y = a3.y / (l3 + 1e-16f) + bi3.y;
    *(float2*)&out3[(size_t)wv * 32 + c2] = o;
  }
  if (lane == 0) logits[wv] = a2 / (l2 + 1e-16f) + bias2[0];
}

// ---------------- node categorical: 64-block partial + 1-wave final ----------------
#define NSB 64
__global__ __launch_bounds__(256) void node_partial_kernel(const float* __restrict__ logits,
    int N, uint32_t ka, uint32_t kb,
    float* __restrict__ pB, int* __restrict__ pI,
    float* __restrict__ pM, float* __restrict__ pL) {
  int chunk = (N + NSB - 1) / NSB;
  int s0 = blockIdx.x * chunk;
  int s1 = s0 + chunk; if (s1 > N) s1 = N;
  int tid = threadIdx.x;
  float best = -INFINITY; int bi = 0x7fffffff;
  float m = -INFINITY, l = 0.f;
  for (int i = s0 + tid; i < s1; i += 256) {
    float lg = logits[i];
    float mn = fmaxf(m, lg);
    l = l * __expf(m - mn) + __expf(lg - mn);
    m = mn;
    float v = lg + gumbel_part(ka, kb, (uint32_t)i);
    if (v > best) { best = v; bi = i; }
  }
  __shared__ float sb[256], sm[256], sl[256];
  __shared__ int si[256];
  sb[tid] = best; si[tid] = bi; sm[tid] = m; sl[tid] = l;
  __syncthreads();
  for (int s = 128; s; s >>= 1) {
    if (tid < s) {
      if (sb[tid + s] > sb[tid] || (sb[tid + s] == sb[tid] && si[tid + s] < si[tid])) {
        sb[tid] = sb[tid + s]; si[tid] = si[tid + s];
      }
      float M = fmaxf(sm[tid], sm[tid + s]);
      float t0 = (sm[tid] == -INFINITY) ? 0.f : sl[tid] * __expf(sm[tid] - M);
      float t1 = (sm[tid + s] == -INFINITY) ? 0.f : sl[tid + s] * __expf(sm[tid + s] - M);
      sm[tid] = M; sl[tid] = t0 + t1;
    }
    __syncthreads();
  }
  if (tid == 0) { pB[blockIdx.x] = sb[0]; pI[blockIdx.x] = si[0]; pM[blockIdx.x] = sm[0]; pL[blockIdx.x] = sl[0]; }
}

__global__ __launch_bounds__(64) void node_final_kernel(const float* __restrict__ logits,
    const float* __restrict__ pB, const int* __restrict__ pI,
    const float* __restrict__ pM, const float* __restrict__ pL,
    float* __restrict__ scal) {
  int lane = threadIdx.x;
  float best = pB[lane]; int bi = pI[lane];
  float m = pM[lane]; float l = pL[lane];
#pragma unroll
  for (int off = 32; off; off >>= 1) {
    float ob = __shfl_xor(best, off); int oi = __shfl_xor(bi, off);
    if (ob > best || (ob == best && oi < bi)) { best = ob; bi = oi; }
    float om = __shfl_xor(m, off); float ol = __shfl_xor(l, off);
    float M = fmaxf(m, om);
    float t0 = (m == -INFINITY) ? 0.f : l * __expf(m - M);
    float t1 = (om == -INFINITY) ? 0.f : ol * __expf(om - M);
    m = M; l = t0 + t1;
  }
  if (lane == 0) {
    ((int*)scal)[0] = bi;
    scal[3] = logits[bi] - (m + logf(l));
  }
}

// ---------------- action categorical + output ----------------
__global__ __launch_bounds__(64) void action_kernel(const float* __restrict__ out3,
    const float* __restrict__ scal, uint32_t ka, uint32_t kb,
    float* __restrict__ dout, int out_size) {
  int lane = threadIdx.x;
  int sel = ((const int*)scal)[0];
  float v = -INFINITY, noisy = -INFINITY;
  if (lane < 32) {
    v = out3[(size_t)sel * 32 + lane];
    noisy = v + gumbel_part(ka, kb, (uint32_t)lane);
  }
  int idx = lane;
  float nv = noisy;
#pragma unroll
  for (int off = 32; off; off >>= 1) {
    float ov = __shfl_xor(nv, off);
    int oi = __shfl_xor(idx, off);
    if (ov > nv || (ov == nv && oi < idx)) { nv = ov; idx = oi; }
  }
  float vm = v;
#pragma unroll
  for (int off = 32; off; off >>= 1) vm = fmaxf(vm, __shfl_xor(vm, off));
  float ex = (lane < 32) ? expf(v - vm) : 0.f;
#pragma unroll
  for (int off = 32; off; off >>= 1) ex += __shfl_xor(ex, off);
  float vsel = __shfl(v, idx);
  if (lane == 0) {
    float action_lp = vsel - vm - logf(ex);
    dout[0] = (float)sel;
    dout[1] = (float)idx;
    dout[2] = scal[3] + action_lp;
  }
  for (int i = 3 + lane; i < out_size; i += 64) dout[i] = 0.f;
}

extern "C" void kernel_launch(void* const* d_in, const int* in_sizes, int n_in,
                              void* d_out, int out_size, void* d_ws, size_t ws_size,
                              hipStream_t stream) {
  const float* x     = (const float*)d_in[0];
  const int*   ei    = (const int*)d_in[1];
  const float* ea    = (const float*)d_in[2];
  const float* Wl1   = (const float*)d_in[3];
  const float* bl1   = (const float*)d_in[4];
  const float* We1   = (const float*)d_in[5];
  const float* att1  = (const float*)d_in[6];
  const float* bias1 = (const float*)d_in[7];
  const float* Wl2   = (const float*)d_in[8];
  const float* bl2   = (const float*)d_in[9];
  const float* We2   = (const float*)d_in[10];
  const float* att2  = (const float*)d_in[11];
  const float* bias2 = (const float*)d_in[12];
  const float* Wl3   = (const float*)d_in[13];
  const float* bl3   = (const float*)d_in[14];
  const float* We3   = (const float*)d_in[15];
  const float* att3  = (const float*)d_in[16];
  const float* bias3 = (const float*)d_in[17];
  int N = in_sizes[0] / 128;
  int E = in_sizes[1] / 2;
  float* out = (float*)d_out;

  char* p = (char*)d_ws;
  auto alloc = [&](size_t bytes) -> char* {
    char* r = p; p += (bytes + 255) & ~(size_t)255; return r;
  };
  float* h1      = (float*)alloc((size_t)N * 128 * 4);
  float* latent  = (float*)alloc((size_t)N * 128 * 4);
  float* h3      = (float*)alloc((size_t)N * 32 * 4);
  float* h2      = (float*)alloc((size_t)N * 4);
  float* logits  = (float*)alloc((size_t)N * 4);
  float* out3    = (float*)alloc((size_t)N * 32 * 4);
  int* counts    = (int*)alloc((size_t)N * 4);
  int* row_start = (int*)alloc((size_t)(N + 1) * 4);
  int* cursor    = (int*)alloc((size_t)N * 4);
  int* src_csr   = (int*)alloc((size_t)E * 4);
  float* ea_csr  = (float*)alloc((size_t)E * 16 * 4);
  float* pB      = (float*)alloc(NSB * 4);
  int*   pI      = (int*)alloc(NSB * 4);
  float* pM      = (float*)alloc(NSB * 4);
  float* pL      = (float*)alloc(NSB * 4);
  float* scal    = (float*)alloc(64);
  (void)ws_size; (void)n_in;

  // JAX PRNG (partitionable): key(42)=(0,42); subkey_i = TF(key,(0,i))
  uint32_t k1a, k1b, k2a, k2b;
  threefry2x32(0u, 42u, 0u, 0u, &k1a, &k1b);
  threefry2x32(0u, 42u, 0u, 1u, &k2a, &k2b);

  hipMemsetAsync(counts, 0, (size_t)N * 4, stream);
  count_kernel<<<(E + 255) / 256, 256, 0, stream>>>(ei, E, counts);
  scan_kernel<<<1, 1024, 0, stream>>>(counts, row_start, cursor, N, E);
  scatter_kernel<<<(E + 255) / 256, 256, 0, stream>>>(ei, ea, E, cursor, src_csr, ea_csr);

  gemm128_kernel<<<(N + 31) / 32, 256, 0, stream>>>(x, Wl1, bl1, h1, N);
  fused1_kernel<<<(N + 15) / 16, 256, 0, stream>>>(h1, src_csr, row_start,
                                                   ea_csr, We1, att1, bias1, latent, N);

  gemm32_kernel<<<((size_t)N * 32 + 255) / 256, 256, 0, stream>>>(latent, Wl3, bl3, h3, N);
  gemv_kernel<<<(N + 3) / 4, 256, 0, stream>>>(latent, Wl2, bl2, h2, N);

  fused23_kernel<<<(N + 3) / 4, 256, 0, stream>>>(h3, h2, src_csr, row_start, ea_csr,
                                                  We3, att3, bias3, We2, att2, bias2,
                                                  out3, logits, N);

  node_partial_kernel<<<NSB, 256, 0, stream>>>(logits, N, k1a, k1b, pB, pI, pM, pL);
  node_final_kernel<<<1, 64, 0, stream>>>(logits, pB, pI, pM, pL, scal);
  action_kernel<<<1, 64, 0, stream>>>(out3, scal, k2a, k2b, out, out_size);
}

// Round 9
// 626.172 us; speedup vs baseline: 1.2021x; 1.2021x over previous
//
#include <hip/hip_runtime.h>
#include <stdint.h>
#include <math.h>

#define NEG 0.2f
#define TINYF 1.1754943508222875e-38f

// ---------------- Threefry-2x32-20 (matches JAX) ----------------
__host__ __device__ inline void threefry2x32(uint32_t k0, uint32_t k1,
                                             uint32_t x0, uint32_t x1,
                                             uint32_t* o0, uint32_t* o1) {
  uint32_t ks0 = k0, ks1 = k1, ks2 = k0 ^ k1 ^ 0x1BD11BDAu;
  x0 += ks0; x1 += ks1;
#define RR(r) { x0 += x1; x1 = (x1 << (r)) | (x1 >> (32 - (r))); x1 ^= x0; }
  RR(13) RR(15) RR(26) RR(6)
  x0 += ks1; x1 += ks2 + 1u;
  RR(17) RR(29) RR(16) RR(24)
  x0 += ks2; x1 += ks0 + 2u;
  RR(13) RR(15) RR(26) RR(6)
  x0 += ks0; x1 += ks1 + 3u;
  RR(17) RR(29) RR(16) RR(24)
  x0 += ks1; x1 += ks2 + 4u;
  RR(13) RR(15) RR(26) RR(6)
  x0 += ks2; x1 += ks0 + 5u;
#undef RR
  *o0 = x0; *o1 = x1;
}

// jax_threefry_partitionable=True random_bits, bit_width=32:
//   bits[i] = o0 ^ o1 of TF(key, (0, i))   [verified exact: R3-R8 pass]
__device__ inline float gumbel_part(uint32_t ka, uint32_t kb, uint32_t i) {
  uint32_t o0, o1;
  threefry2x32(ka, kb, 0u, i, &o0, &o1);
  uint32_t bits = o0 ^ o1;
  float f = __uint_as_float((bits >> 9) | 0x3f800000u) - 1.0f;
  float u = fmaxf(TINYF, f + TINYF);
  return -logf(-logf(u));
}

// ---------------- CSR build ----------------
__global__ void count_kernel(const int* __restrict__ ei, int E, int* __restrict__ counts) {
  int e = blockIdx.x * blockDim.x + threadIdx.x;
  if (e < E) atomicAdd(&counts[ei[E + e]], 1);
}

__global__ __launch_bounds__(1024) void scan_kernel(const int* __restrict__ counts,
    int* __restrict__ row_start, int* __restrict__ cursor, int N, int E) {
  __shared__ int wsum[16];
  __shared__ int base_s;
  int tid = threadIdx.x;
  int lane = tid & 63, wv = tid >> 6;
  if (tid == 0) base_s = 0;
  __syncthreads();
  for (int chunk = 0; chunk < N; chunk += 1024) {
    int i = chunk + tid;
    int v = (i < N) ? counts[i] : 0;
    int incl = v;
#pragma unroll
    for (int off = 1; off < 64; off <<= 1) {
      int t = __shfl_up(incl, off);
      if (lane >= off) incl += t;
    }
    if (lane == 63) wsum[wv] = incl;
    __syncthreads();
    if (wv == 0) {
      int x = (lane < 16) ? wsum[lane] : 0;
#pragma unroll
      for (int off = 1; off < 16; off <<= 1) {
        int t = __shfl_up(x, off);
        if (lane >= off) x += t;
      }
      if (lane < 16) wsum[lane] = x;
    }
    __syncthreads();
    int waveoff = (wv == 0) ? 0 : wsum[wv - 1];
    int base = base_s;
    int excl = base + waveoff + incl - v;
    if (i < N) { row_start[i] = excl; cursor[i] = excl; }
    __syncthreads();
    if (tid == 1023) base_s = base + wsum[15];
    __syncthreads();
  }
  if (tid == 0) row_start[N] = base_s;
}

// scatter: src_csr + ea permuted into CSR order (streamed reads downstream)
__global__ void scatter_kernel(const int* __restrict__ ei, const float* __restrict__ ea,
                               int E, int* __restrict__ cursor,
                               int* __restrict__ src_csr, float* __restrict__ ea_csr) {
  int e = blockIdx.x * blockDim.x + threadIdx.x;
  if (e < E) {
    int d = ei[E + e];
    int p = atomicAdd(&cursor[d], 1);
    src_csr[p] = ei[e];
    const float4* s4 = (const float4*)&ea[(size_t)e * 16];
    float4* d4 = (float4*)&ea_csr[(size_t)p * 16];
    float4 t0 = s4[0], t1 = s4[1], t2 = s4[2], t3 = s4[3];
    d4[0] = t0; d4[1] = t1; d4[2] = t2; d4[3] = t3;
  }
}

// ---------------- h = X @ W (128x128) + b ----------------
__global__ __launch_bounds__(256) void gemm128_kernel(const float* __restrict__ X,
    const float* __restrict__ W, const float* __restrict__ bias,
    float* __restrict__ out, int M) {
  __shared__ float xs[128][33];
  int row0 = blockIdx.x * 32;
  int tid = threadIdx.x;
  for (int idx = tid; idx < 32 * 128; idx += 256) {
    int r = idx >> 7;
    int k = idx & 127;
    int row = row0 + r;
    xs[k][r] = (row < M) ? X[(size_t)row * 128 + k] : 0.0f;
  }
  __syncthreads();
  int tc = tid & 31, tr = tid >> 5;
  int c0 = tc * 4, r0 = tr * 4;
  float acc[4][4] = {};
#pragma unroll 4
  for (int k = 0; k < 128; k++) {
    float4 w = *(const float4*)&W[k * 128 + c0];
    float x0 = xs[k][r0], x1 = xs[k][r0 + 1], x2 = xs[k][r0 + 2], x3 = xs[k][r0 + 3];
    acc[0][0] += x0 * w.x; acc[0][1] += x0 * w.y; acc[0][2] += x0 * w.z; acc[0][3] += x0 * w.w;
    acc[1][0] += x1 * w.x; acc[1][1] += x1 * w.y; acc[1][2] += x1 * w.z; acc[1][3] += x1 * w.w;
    acc[2][0] += x2 * w.x; acc[2][1] += x2 * w.y; acc[2][2] += x2 * w.z; acc[2][3] += x2 * w.w;
    acc[3][0] += x3 * w.x; acc[3][1] += x3 * w.y; acc[3][2] += x3 * w.z; acc[3][3] += x3 * w.w;
  }
  float4 b4 = *(const float4*)&bias[c0];
  for (int r = 0; r < 4; r++) {
    int row = row0 + r0 + r;
    if (row < M) {
      float4 o;
      o.x = acc[r][0] + b4.x; o.y = acc[r][1] + b4.y;
      o.z = acc[r][2] + b4.z; o.w = acc[r][3] + b4.w;
      *(float4*)&out[(size_t)row * 128 + c0] = o;
    }
  }
}

// ---------------- h3 = latent @ Wl3 (128x32) + b ----------------
__global__ __launch_bounds__(256) void gemm32_kernel(const float* __restrict__ X,
    const float* __restrict__ W, const float* __restrict__ bias,
    float* __restrict__ out, int M) {
  int t = blockIdx.x * 256 + threadIdx.x;
  int node = t >> 5, c = t & 31;
  if (node >= M) return;
  const float4* xp = (const float4*)&X[(size_t)node * 128];
  float acc = 0.f;
#pragma unroll
  for (int q = 0; q < 32; q++) {
    float4 x4 = xp[q];
    acc += x4.x * W[(q * 4 + 0) * 32 + c] + x4.y * W[(q * 4 + 1) * 32 + c]
         + x4.z * W[(q * 4 + 2) * 32 + c] + x4.w * W[(q * 4 + 3) * 32 + c];
  }
  out[(size_t)node * 32 + c] = acc + bias[c];
}

// ---------------- h2 = latent @ Wl2 (128x1) + b ----------------
__global__ __launch_bounds__(256) void gemv_kernel(const float* __restrict__ X,
    const float* __restrict__ w, const float* __restrict__ b0,
    float* __restrict__ out, int M) {
  int wv = (blockIdx.x * 256 + threadIdx.x) >> 6;
  int lane = threadIdx.x & 63;
  if (wv >= M) return;
  float2 xv = *(const float2*)&X[(size_t)wv * 128 + lane * 2];
  float2 wvv = *(const float2*)&w[lane * 2];
  float v = xv.x * wvv.x + xv.y * wvv.y;
#pragma unroll
  for (int off = 32; off; off >>= 1) v += __shfl_xor(v, off);
  if (lane == 0) out[wv] = v + b0[0];
}

// ---------------- layer-1 fused (HALF-wave per node, float4 lanes, LDS We) ----------------
// R7-proven configuration: 170 us, VGPR 64, zero LDS bank conflicts.
__global__ __launch_bounds__(256) void fused1_kernel(const float* __restrict__ h,
    const int* __restrict__ src_csr, const int* __restrict__ row_start,
    const float* __restrict__ ea_csr,
    const float* __restrict__ We, const float* __restrict__ att,
    const float* __restrict__ bias, float* __restrict__ out, int N) {
  __shared__ float WeS[2048];
  int tid = threadIdx.x;
  for (int i = tid; i < 2048; i += 256) WeS[i] = We[i];
  __syncthreads();
  int hw = (blockIdx.x * 256 + tid) >> 5;   // half-wave = one node
  int lane = tid & 31;
  if (hw >= N) return;
  int c4 = lane * 4;
  float4 attv = *(const float4*)&att[c4];
  float4 b4 = *(const float4*)&bias[c4];
  int start = row_start[hw];
  int deg = row_start[hw + 1] - start;
  if (deg == 0) {
    *(float4*)&out[(size_t)hw * 128 + c4] = b4;
    return;
  }
  float4 hi = *(const float4*)&h[(size_t)hw * 128 + c4];
  int s_l = (lane < deg) ? src_csr[start + lane] : 0;
  int dcap = deg < 32 ? deg : 32;
  const float4* eap = (const float4*)&ea_csr[(size_t)start * 16];
  float m = -INFINITY, l = 0.f;
  float4 acc = make_float4(0.f, 0.f, 0.f, 0.f);
  for (int j = 0; j < deg; j++) {
    int s = (j < dcap) ? __shfl(s_l, j, 32) : src_csr[start + j];
    float4 hj = *(const float4*)&h[(size_t)s * 128 + c4];
    float4 v;
    v.x = hi.x + hj.x; v.y = hi.y + hj.y; v.z = hi.z + hj.z; v.w = hi.w + hj.w;
#pragma unroll
    for (int q = 0; q < 4; q++) {
      float4 aq = eap[(size_t)j * 4 + q];
      float4 w0 = *(const float4*)&WeS[(4 * q + 0) * 128 + c4];
      float4 w1 = *(const float4*)&WeS[(4 * q + 1) * 128 + c4];
      float4 w2 = *(const float4*)&WeS[(4 * q + 2) * 128 + c4];
      float4 w3 = *(const float4*)&WeS[(4 * q + 3) * 128 + c4];
      v.x += aq.x * w0.x + aq.y * w1.x + aq.z * w2.x + aq.w * w3.x;
      v.y += aq.x * w0.y + aq.y * w1.y + aq.z * w2.y + aq.w * w3.y;
      v.z += aq.x * w0.z + aq.y * w1.z + aq.z * w2.z + aq.w * w3.z;
      v.w += aq.x * w0.w + aq.y * w1.w + aq.z * w2.w + aq.w * w3.w;
    }
    v.x = v.x >= 0.f ? v.x : NEG * v.x;
    v.y = v.y >= 0.f ? v.y : NEG * v.y;
    v.z = v.z >= 0.f ? v.z : NEG * v.z;
    v.w = v.w >= 0.f ? v.w : NEG * v.w;
    float sc = v.x * attv.x + v.y * attv.y + v.z * attv.z + v.w * attv.w;
#pragma unroll
    for (int off = 16; off; off >>= 1) sc += __shfl_xor(sc, off);
    float mn = fmaxf(m, sc);
    float scale = __expf(m - mn);   // first edge: exp(-inf)=0
    float w = __expf(sc - mn);
    l = l * scale + w;
    acc.x = acc.x * scale + w * hj.x;
    acc.y = acc.y * scale + w * hj.y;
    acc.z = acc.z * scale + w * hj.z;
    acc.w = acc.w * scale + w * hj.w;
    m = mn;
  }
  float inv = 1.0f / (l + 1e-16f);
  float4 o;
  o.x = acc.x * inv + b4.x;
  o.y = acc.y * inv + b4.y;
  o.z = acc.z * inv + b4.z;
  o.w = acc.w * inv + b4.w;
  *(float4*)&out[(size_t)hw * 128 + c4] = o;
}

// ---------------- layers 2+3 fused (wave/node, QUARTER-wave per edge: 4 in flight) ----------------
// R8-proven configuration (faster than R7's half-wave variant).
__global__ __launch_bounds__(256) void fused23_kernel(
    const float* __restrict__ h3, const float* __restrict__ h2,
    const int* __restrict__ src_csr, const int* __restrict__ row_start,
    const float* __restrict__ ea_csr,
    const float* __restrict__ We3, const float* __restrict__ att3,
    const float* __restrict__ bias3, const float* __restrict__ We2,
    const float* __restrict__ att2, const float* __restrict__ bias2,
    float* __restrict__ out3, float* __restrict__ logits, int N) {
  int tid = threadIdx.x;
  int wv = (blockIdx.x * 256 + tid) >> 6;
  int lane = tid & 63;
  if (wv >= N) return;
  int q4 = lane >> 4;        // quarter index 0..3
  int l16 = lane & 15;
  int c2 = l16 * 2;          // 2 dims per lane (32 dims / 16 lanes)
  float2 we3[16];
#pragma unroll
  for (int k = 0; k < 16; k++) we3[k] = *(const float2*)&We3[k * 32 + c2];
  float we2[16];
#pragma unroll
  for (int k = 0; k < 16; k++) we2[k] = We2[k];
  float2 at3 = *(const float2*)&att3[c2];
  float a2s = att2[0];
  float2 bi3 = *(const float2*)&bias3[c2];
  int start = row_start[wv];
  int deg = row_start[wv + 1] - start;
  if (deg == 0) {
    if (lane < 16) *(float2*)&out3[(size_t)wv * 32 + c2] = bi3;
    if (lane == 0) logits[wv] = bias2[0];
    return;
  }
  float2 hi3 = *(const float2*)&h3[(size_t)wv * 32 + c2];
  float hi2 = h2[wv];
  int s_l = (lane < deg) ? src_csr[start + lane] : 0;
  int dcap = deg < 64 ? deg : 64;
  const float4* eap = (const float4*)&ea_csr[(size_t)start * 16];
  float m3 = -INFINITY, l3 = 0.f; float2 a3 = make_float2(0.f, 0.f);
  float m2 = -INFINITY, l2 = 0.f; float a2 = 0.f;
  for (int j = q4; j < deg; j += 4) {
    int s = (j < dcap) ? __shfl(s_l, j) : src_csr[start + j];
    float2 hj3 = *(const float2*)&h3[(size_t)s * 32 + c2];
    float h2s = h2[s];
    float4 c0 = eap[(size_t)j * 4 + 0];
    float4 c1 = eap[(size_t)j * 4 + 1];
    float4 cc2 = eap[(size_t)j * 4 + 2];
    float4 c3 = eap[(size_t)j * 4 + 3];
    float vx = hi3.x + hj3.x, vy = hi3.y + hj3.y;
    vx += c0.x * we3[0].x + c0.y * we3[1].x + c0.z * we3[2].x + c0.w * we3[3].x;
    vy += c0.x * we3[0].y + c0.y * we3[1].y + c0.z * we3[2].y + c0.w * we3[3].y;
    vx += c1.x * we3[4].x + c1.y * we3[5].x + c1.z * we3[6].x + c1.w * we3[7].x;
    vy += c1.x * we3[4].y + c1.y * we3[5].y + c1.z * we3[6].y + c1.w * we3[7].y;
    vx += cc2.x * we3[8].x + cc2.y * we3[9].x + cc2.z * we3[10].x + cc2.w * we3[11].x;
    vy += cc2.x * we3[8].y + cc2.y * we3[9].y + cc2.z * we3[10].y + cc2.w * we3[11].y;
    vx += c3.x * we3[12].x + c3.y * we3[13].x + c3.z * we3[14].x + c3.w * we3[15].x;
    vy += c3.x * we3[12].y + c3.y * we3[13].y + c3.z * we3[14].y + c3.w * we3[15].y;
    vx = vx >= 0.f ? vx : NEG * vx;
    vy = vy >= 0.f ? vy : NEG * vy;
    float t3 = vx * at3.x + vy * at3.y;
#pragma unroll
    for (int off = 8; off; off >>= 1) t3 += __shfl_xor(t3, off);
    float v2 = hi2 + h2s;
    v2 += c0.x * we2[0]  + c0.y * we2[1]  + c0.z * we2[2]  + c0.w * we2[3];
    v2 += c1.x * we2[4]  + c1.y * we2[5]  + c1.z * we2[6]  + c1.w * we2[7];
    v2 += cc2.x * we2[8] + cc2.y * we2[9] + cc2.z * we2[10] + cc2.w * we2[11];
    v2 += c3.x * we2[12] + c3.y * we2[13] + c3.z * we2[14] + c3.w * we2[15];
    v2 = v2 >= 0.f ? v2 : NEG * v2;
    float t2 = v2 * a2s;
    float mn3 = fmaxf(m3, t3);
    float sc3 = __expf(m3 - mn3);
    float w3 = __expf(t3 - mn3);
    l3 = l3 * sc3 + w3;
    a3.x = a3.x * sc3 + w3 * hj3.x;
    a3.y = a3.y * sc3 + w3 * hj3.y;
    m3 = mn3;
    float mn2 = fmaxf(m2, t2);
    float sc2 = __expf(m2 - mn2);
    float w2 = __expf(t2 - mn2);
    l2 = l2 * sc2 + w2;
    a2 = a2 * sc2 + w2 * h2s;
    m2 = mn2;
  }
  // merge 4 quarter states (xor 16 then 32); quarter 0 has >=1 edge
#pragma unroll
  for (int off = 16; off <= 32; off <<= 1) {
    float m3o = __shfl_xor(m3, off), l3o = __shfl_xor(l3, off);
    float ax = __shfl_xor(a3.x, off), ay = __shfl_xor(a3.y, off);
    float M3 = fmaxf(m3, m3o);
    float sA = (m3 == -INFINITY) ? 0.f : __expf(m3 - M3);
    float sB = (m3o == -INFINITY) ? 0.f : __expf(m3o - M3);
    l3 = l3 * sA + l3o * sB;
    a3.x = a3.x * sA + ax * sB;
    a3.y = a3.y * sA + ay * sB;
    m3 = M3;
    float m2o = __shfl_xor(m2, off), l2o = __shfl_xor(l2, off);
    float az = __shfl_xor(a2, off);
    float M2 = fmaxf(m2, m2o);
    float tA = (m2 == -INFINITY) ? 0.f : __expf(m2 - M2);
    float tB = (m2o == -INFINITY) ? 0.f : __expf(m2o - M2);
    l2 = l2 * tA + l2o * tB;
    a2 = a2 * tA + az * tB;
    m2 = M2;
  }
  if (lane < 16) {
    float2 o;
    o.x = a3.x / (l3 + 1e-16f) + bi3.x;
    o.y = a3.y / (l3 + 1e-16f) + bi3.y;
    *(float2*)&out3[(size_t)wv * 32 + c2] = o;
  }
  if (lane == 0) logits[wv] = a2 / (l2 + 1e-16f) + bias2[0];
}

// ---------------- node categorical: 64-block partial + 1-wave final ----------------
#define NSB 64
__global__ __launch_bounds__(256) void node_partial_kernel(const float* __restrict__ logits,
    int N, uint32_t ka, uint32_t kb,
    float* __restrict__ pB, int* __restrict__ pI,
    float* __restrict__ pM, float* __restrict__ pL) {
  int chunk = (N + NSB - 1) / NSB;
  int s0 = blockIdx.x * chunk;
  int s1 = s0 + chunk; if (s1 > N) s1 = N;
  int tid = threadIdx.x;
  float best = -INFINITY; int bi = 0x7fffffff;
  float m = -INFINITY, l = 0.f;
  for (int i = s0 + tid; i < s1; i += 256) {
    float lg = logits[i];
    float mn = fmaxf(m, lg);
    l = l * __expf(m - mn) + __expf(lg - mn);
    m = mn;
    float v = lg + gumbel_part(ka, kb, (uint32_t)i);
    if (v > best) { best = v; bi = i; }
  }
  __shared__ float sb[256], sm[256], sl[256];
  __shared__ int si[256];
  sb[tid] = best; si[tid] = bi; sm[tid] = m; sl[tid] = l;
  __syncthreads();
  for (int s = 128; s; s >>= 1) {
    if (tid < s) {
      if (sb[tid + s] > sb[tid] || (sb[tid + s] == sb[tid] && si[tid + s] < si[tid])) {
        sb[tid] = sb[tid + s]; si[tid] = si[tid + s];
      }
      float M = fmaxf(sm[tid], sm[tid + s]);
      float t0 = (sm[tid] == -INFINITY) ? 0.f : sl[tid] * __expf(sm[tid] - M);
      float t1 = (sm[tid + s] == -INFINITY) ? 0.f : sl[tid + s] * __expf(sm[tid + s] - M);
      sm[tid] = M; sl[tid] = t0 + t1;
    }
    __syncthreads();
  }
  if (tid == 0) { pB[blockIdx.x] = sb[0]; pI[blockIdx.x] = si[0]; pM[blockIdx.x] = sm[0]; pL[blockIdx.x] = sl[0]; }
}

__global__ __launch_bounds__(64) void node_final_kernel(const float* __restrict__ logits,
    const float* __restrict__ pB, const int* __restrict__ pI,
    const float* __restrict__ pM, const float* __restrict__ pL,
    float* __restrict__ scal) {
  int lane = threadIdx.x;
  float best = pB[lane]; int bi = pI[lane];
  float m = pM[lane]; float l = pL[lane];
#pragma unroll
  for (int off = 32; off; off >>= 1) {
    float ob = __shfl_xor(best, off); int oi = __shfl_xor(bi, off);
    if (ob > best || (ob == best && oi < bi)) { best = ob; bi = oi; }
    float om = __shfl_xor(m, off); float ol = __shfl_xor(l, off);
    float M = fmaxf(m, om);
    float t0 = (m == -INFINITY) ? 0.f : l * __expf(m - M);
    float t1 = (om == -INFINITY) ? 0.f : ol * __expf(om - M);
    m = M; l = t0 + t1;
  }
  if (lane == 0) {
    ((int*)scal)[0] = bi;
    scal[3] = logits[bi] - (m + logf(l));
  }
}

// ---------------- action categorical + output ----------------
__global__ __launch_bounds__(64) void action_kernel(const float* __restrict__ out3,
    const float* __restrict__ scal, uint32_t ka, uint32_t kb,
    float* __restrict__ dout, int out_size) {
  int lane = threadIdx.x;
  int sel = ((const int*)scal)[0];
  float v = -INFINITY, noisy = -INFINITY;
  if (lane < 32) {
    v = out3[(size_t)sel * 32 + lane];
    noisy = v + gumbel_part(ka, kb, (uint32_t)lane);
  }
  int idx = lane;
  float nv = noisy;
#pragma unroll
  for (int off = 32; off; off >>= 1) {
    float ov = __shfl_xor(nv, off);
    int oi = __shfl_xor(idx, off);
    if (ov > nv || (ov == nv && oi < idx)) { nv = ov; idx = oi; }
  }
  float vm = v;
#pragma unroll
  for (int off = 32; off; off >>= 1) vm = fmaxf(vm, __shfl_xor(vm, off));
  float ex = (lane < 32) ? expf(v - vm) : 0.f;
#pragma unroll
  for (int off = 32; off; off >>= 1) ex += __shfl_xor(ex, off);
  float vsel = __shfl(v, idx);
  if (lane == 0) {
    float action_lp = vsel - vm - logf(ex);
    dout[0] = (float)sel;
    dout[1] = (float)idx;
    dout[2] = scal[3] + action_lp;
  }
  for (int i = 3 + lane; i < out_size; i += 64) dout[i] = 0.f;
}

extern "C" void kernel_launch(void* const* d_in, const int* in_sizes, int n_in,
                              void* d_out, int out_size, void* d_ws, size_t ws_size,
                              hipStream_t stream) {
  const float* x     = (const float*)d_in[0];
  const int*   ei    = (const int*)d_in[1];
  const float* ea    = (const float*)d_in[2];
  const float* Wl1   = (const float*)d_in[3];
  const float* bl1   = (const float*)d_in[4];
  const float* We1   = (const float*)d_in[5];
  const float* att1  = (const float*)d_in[6];
  const float* bias1 = (const float*)d_in[7];
  const float* Wl2   = (const float*)d_in[8];
  const float* bl2   = (const float*)d_in[9];
  const float* We2   = (const float*)d_in[10];
  const float* att2  = (const float*)d_in[11];
  const float* bias2 = (const float*)d_in[12];
  const float* Wl3   = (const float*)d_in[13];
  const float* bl3   = (const float*)d_in[14];
  const float* We3   = (const float*)d_in[15];
  const float* att3  = (const float*)d_in[16];
  const float* bias3 = (const float*)d_in[17];
  int N = in_sizes[0] / 128;
  int E = in_sizes[1] / 2;
  float* out = (float*)d_out;

  char* p = (char*)d_ws;
  auto alloc = [&](size_t bytes) -> char* {
    char* r = p; p += (bytes + 255) & ~(size_t)255; return r;
  };
  float* h1      = (float*)alloc((size_t)N * 128 * 4);
  float* latent  = (float*)alloc((size_t)N * 128 * 4);
  float* h3      = (float*)alloc((size_t)N * 32 * 4);
  float* h2      = (float*)alloc((size_t)N * 4);
  float* logits  = (float*)alloc((size_t)N * 4);
  float* out3    = (float*)alloc((size_t)N * 32 * 4);
  int* counts    = (int*)alloc((size_t)N * 4);
  int* row_start = (int*)alloc((size_t)(N + 1) * 4);
  int* cursor    = (int*)alloc((size_t)N * 4);
  int* src_csr   = (int*)alloc((size_t)E * 4);
  float* ea_csr  = (float*)alloc((size_t)E * 16 * 4);
  float* pB      = (float*)alloc(NSB * 4);
  int*   pI      = (int*)alloc(NSB * 4);
  float* pM      = (float*)alloc(NSB * 4);
  float* pL      = (float*)alloc(NSB * 4);
  float* scal    = (float*)alloc(64);
  (void)ws_size; (void)n_in;

  // JAX PRNG (partitionable): key(42)=(0,42); subkey_i = TF(key,(0,i))
  uint32_t k1a, k1b, k2a, k2b;
  threefry2x32(0u, 42u, 0u, 0u, &k1a, &k1b);
  threefry2x32(0u, 42u, 0u, 1u, &k2a, &k2b);

  hipMemsetAsync(counts, 0, (size_t)N * 4, stream);
  count_kernel<<<(E + 255) / 256, 256, 0, stream>>>(ei, E, counts);
  scan_kernel<<<1, 1024, 0, stream>>>(counts, row_start, cursor, N, E);
  scatter_kernel<<<(E + 255) / 256, 256, 0, stream>>>(ei, ea, E, cursor, src_csr, ea_csr);

  gemm128_kernel<<<(N + 31) / 32, 256, 0, stream>>>(x, Wl1, bl1, h1, N);
  fused1_kernel<<<(N + 7) / 8, 256, 0, stream>>>(h1, src_csr, row_start,
                                                 ea_csr, We1, att1, bias1, latent, N);

  gemm32_kernel<<<((size_t)N * 32 + 255) / 256, 256, 0, stream>>>(latent, Wl3, bl3, h3, N);
  gemv_kernel<<<(N + 3) / 4, 256, 0, stream>>>(latent, Wl2, bl2, h2, N);

  fused23_kernel<<<(N + 3) / 4, 256, 0, stream>>>(h3, h2, src_csr, row_start, ea_csr,
                                                  We3, att3, bias3, We2, att2, bias2,
                                                  out3, logits, N);

  node_partial_kernel<<<NSB, 256, 0, stream>>>(logits, N, k1a, k1b, pB, pI, pM, pL);
  node_final_kernel<<<1, 64, 0, stream>>>(logits, pB, pI, pM, pL, scal);
  action_kernel<<<1, 64, 0, stream>>>(out3, scal, k2a, k2b, out, out_size);
}

// Round 10
// 584.579 us; speedup vs baseline: 1.2877x; 1.0711x over previous
//
#include <hip/hip_runtime.h>
#include <stdint.h>
#include <math.h>

#define NEG 0.2f
#define TINYF 1.1754943508222875e-38f

typedef float f4 __attribute__((ext_vector_type(4)));
typedef float f2 __attribute__((ext_vector_type(2)));

// ---------------- Threefry-2x32-20 (matches JAX) ----------------
__host__ __device__ inline void threefry2x32(uint32_t k0, uint32_t k1,
                                             uint32_t x0, uint32_t x1,
                                             uint32_t* o0, uint32_t* o1) {
  uint32_t ks0 = k0, ks1 = k1, ks2 = k0 ^ k1 ^ 0x1BD11BDAu;
  x0 += ks0; x1 += ks1;
#define RR(r) { x0 += x1; x1 = (x1 << (r)) | (x1 >> (32 - (r))); x1 ^= x0; }
  RR(13) RR(15) RR(26) RR(6)
  x0 += ks1; x1 += ks2 + 1u;
  RR(17) RR(29) RR(16) RR(24)
  x0 += ks2; x1 += ks0 + 2u;
  RR(13) RR(15) RR(26) RR(6)
  x0 += ks0; x1 += ks1 + 3u;
  RR(17) RR(29) RR(16) RR(24)
  x0 += ks1; x1 += ks2 + 4u;
  RR(13) RR(15) RR(26) RR(6)
  x0 += ks2; x1 += ks0 + 5u;
#undef RR
  *o0 = x0; *o1 = x1;
}

// jax_threefry_partitionable=True random_bits, bit_width=32:
//   bits[i] = o0 ^ o1 of TF(key, (0, i))   [verified exact: R3-R9 pass]
__device__ inline float gumbel_part(uint32_t ka, uint32_t kb, uint32_t i) {
  uint32_t o0, o1;
  threefry2x32(ka, kb, 0u, i, &o0, &o1);
  uint32_t bits = o0 ^ o1;
  float f = __uint_as_float((bits >> 9) | 0x3f800000u) - 1.0f;
  float u = fmaxf(TINYF, f + TINYF);
  return -logf(-logf(u));
}

// ---------------- CSR build ----------------
__global__ void count_kernel(const int* __restrict__ ei, int E, int* __restrict__ counts) {
  int e = blockIdx.x * blockDim.x + threadIdx.x;
  if (e < E) atomicAdd(&counts[ei[E + e]], 1);
}

// parallel scan, 3 phases
#define SCB 256
__global__ __launch_bounds__(256) void scan_partial_kernel(const int* __restrict__ counts,
    int N, int chunk, int* __restrict__ bsum) {
  int b = blockIdx.x;
  int s0 = b * chunk, s1 = s0 + chunk; if (s1 > N) s1 = N;
  int tid = threadIdx.x;
  int v = 0;
  for (int i = s0 + tid; i < s1; i += 256) v += counts[i];
  __shared__ int red[256];
  red[tid] = v; __syncthreads();
  for (int s = 128; s; s >>= 1) { if (tid < s) red[tid] += red[tid + s]; __syncthreads(); }
  if (tid == 0) bsum[b] = red[0];
}

__global__ __launch_bounds__(256) void scan_offsets_kernel(const int* __restrict__ bsum,
    int* __restrict__ boff, int* __restrict__ row_start, int N) {
  int tid = threadIdx.x; int lane = tid & 63; int wv = tid >> 6;
  __shared__ int wsum[4];
  int v = bsum[tid];
  int incl = v;
#pragma unroll
  for (int off = 1; off < 64; off <<= 1) {
    int t = __shfl_up(incl, off);
    if (lane >= off) incl += t;
  }
  if (lane == 63) wsum[wv] = incl;
  __syncthreads();
  if (tid == 0) {
    int s = 0;
    for (int k = 0; k < 4; k++) { int t = wsum[k]; wsum[k] = s; s += t; }
    row_start[N] = s;
  }
  __syncthreads();
  boff[tid] = wsum[wv] + incl - v;
}

__global__ __launch_bounds__(256) void scan_apply_kernel(const int* __restrict__ counts,
    const int* __restrict__ boff, int N, int chunk,
    int* __restrict__ row_start, int* __restrict__ cursor) {
  int b = blockIdx.x;
  int s0 = b * chunk, s1 = s0 + chunk; if (s1 > N) s1 = N;
  int tid = threadIdx.x; int lane = tid & 63; int wv = tid >> 6;
  __shared__ int wsum[4];
  __shared__ int tot_s;
  __shared__ int base_s;
  if (tid == 0) base_s = boff[b];
  __syncthreads();
  for (int c0 = s0; c0 < s1; c0 += 256) {
    int i = c0 + tid;
    int v = (i < s1) ? counts[i] : 0;
    int incl = v;
#pragma unroll
    for (int off = 1; off < 64; off <<= 1) {
      int t = __shfl_up(incl, off);
      if (lane >= off) incl += t;
    }
    if (lane == 63) wsum[wv] = incl;
    __syncthreads();
    if (tid == 0) {
      int s = 0;
      for (int k = 0; k < 4; k++) { int t = wsum[k]; wsum[k] = s; s += t; }
      tot_s = s;
    }
    __syncthreads();
    int base = base_s;
    int excl = base + wsum[wv] + incl - v;
    if (i < s1) { row_start[i] = excl; cursor[i] = excl; }
    __syncthreads();
    if (tid == 0) base_s = base + tot_s;
    __syncthreads();
  }
}

// scatter: src_csr + ea permuted into CSR order (streamed reads downstream)
__global__ void scatter_kernel(const int* __restrict__ ei, const float* __restrict__ ea,
                               int E, int* __restrict__ cursor,
                               int* __restrict__ src_csr, float* __restrict__ ea_csr) {
  int e = blockIdx.x * blockDim.x + threadIdx.x;
  if (e < E) {
    int d = ei[E + e];
    int p = atomicAdd(&cursor[d], 1);
    src_csr[p] = ei[e];
    const float4* s4 = (const float4*)&ea[(size_t)e * 16];
    float4* d4 = (float4*)&ea_csr[(size_t)p * 16];
    float4 t0 = s4[0], t1 = s4[1], t2 = s4[2], t3 = s4[3];
    d4[0] = t0; d4[1] = t1; d4[2] = t2; d4[3] = t3;
  }
}

// ---------------- h = X @ W (128x128) + b ----------------
__global__ __launch_bounds__(256) void gemm128_kernel(const float* __restrict__ X,
    const float* __restrict__ W, const float* __restrict__ bias,
    float* __restrict__ out, int M) {
  __shared__ float xs[128][33];
  int row0 = blockIdx.x * 32;
  int tid = threadIdx.x;
  for (int idx = tid; idx < 32 * 128; idx += 256) {
    int r = idx >> 7;
    int k = idx & 127;
    int row = row0 + r;
    xs[k][r] = (row < M) ? X[(size_t)row * 128 + k] : 0.0f;
  }
  __syncthreads();
  int tc = tid & 31, tr = tid >> 5;
  int c0 = tc * 4, r0 = tr * 4;
  float acc[4][4] = {};
#pragma unroll 4
  for (int k = 0; k < 128; k++) {
    float4 w = *(const float4*)&W[k * 128 + c0];
    float x0 = xs[k][r0], x1 = xs[k][r0 + 1], x2 = xs[k][r0 + 2], x3 = xs[k][r0 + 3];
    acc[0][0] += x0 * w.x; acc[0][1] += x0 * w.y; acc[0][2] += x0 * w.z; acc[0][3] += x0 * w.w;
    acc[1][0] += x1 * w.x; acc[1][1] += x1 * w.y; acc[1][2] += x1 * w.z; acc[1][3] += x1 * w.w;
    acc[2][0] += x2 * w.x; acc[2][1] += x2 * w.y; acc[2][2] += x2 * w.z; acc[2][3] += x2 * w.w;
    acc[3][0] += x3 * w.x; acc[3][1] += x3 * w.y; acc[3][2] += x3 * w.z; acc[3][3] += x3 * w.w;
  }
  float4 b4 = *(const float4*)&bias[c0];
  for (int r = 0; r < 4; r++) {
    int row = row0 + r0 + r;
    if (row < M) {
      float4 o;
      o.x = acc[r][0] + b4.x; o.y = acc[r][1] + b4.y;
      o.z = acc[r][2] + b4.z; o.w = acc[r][3] + b4.w;
      *(float4*)&out[(size_t)row * 128 + c0] = o;
    }
  }
}

// ---------------- h3 = latent @ Wl3 (128x32) + b ----------------
__global__ __launch_bounds__(256) void gemm32_kernel(const float* __restrict__ X,
    const float* __restrict__ W, const float* __restrict__ bias,
    float* __restrict__ out, int M) {
  int t = blockIdx.x * 256 + threadIdx.x;
  int node = t >> 5, c = t & 31;
  if (node >= M) return;
  const float4* xp = (const float4*)&X[(size_t)node * 128];
  float acc = 0.f;
#pragma unroll
  for (int q = 0; q < 32; q++) {
    float4 x4 = xp[q];
    acc += x4.x * W[(q * 4 + 0) * 32 + c] + x4.y * W[(q * 4 + 1) * 32 + c]
         + x4.z * W[(q * 4 + 2) * 32 + c] + x4.w * W[(q * 4 + 3) * 32 + c];
  }
  out[(size_t)node * 32 + c] = acc + bias[c];
}

// ---------------- h2 = latent @ Wl2 (128x1) + b ----------------
__global__ __launch_bounds__(256) void gemv_kernel(const float* __restrict__ X,
    const float* __restrict__ w, const float* __restrict__ b0,
    float* __restrict__ out, int M) {
  int wv = (blockIdx.x * 256 + threadIdx.x) >> 6;
  int lane = threadIdx.x & 63;
  if (wv >= M) return;
  float2 xv = *(const float2*)&X[(size_t)wv * 128 + lane * 2];
  float2 wvv = *(const float2*)&w[lane * 2];
  float v = xv.x * wvv.x + xv.y * wvv.y;
#pragma unroll
  for (int off = 32; off; off >>= 1) v += __shfl_xor(v, off);
  if (lane == 0) out[wv] = v + b0[0];
}

// ---------------- layer-1 fused (HALF-wave per node, packed f4 math, LDS We) ----------------
__global__ __launch_bounds__(256) void fused1_kernel(const float* __restrict__ h,
    const int* __restrict__ src_csr, const int* __restrict__ row_start,
    const float* __restrict__ ea_csr,
    const float* __restrict__ We, const float* __restrict__ att,
    const float* __restrict__ bias, float* __restrict__ out, int N) {
  __shared__ float WeS[2048];
  int tid = threadIdx.x;
  for (int i = tid; i < 2048; i += 256) WeS[i] = We[i];
  __syncthreads();
  int hw = (blockIdx.x * 256 + tid) >> 5;   // half-wave = one node
  int lane = tid & 31;
  if (hw >= N) return;
  int c4 = lane * 4;
  const f4* W4 = (const f4*)WeS;            // row k at W4[k*32 + lane]
  f4 attv = *(const f4*)&att[c4];
  f4 bb = *(const f4*)&bias[c4];
  int start = row_start[hw];
  int deg = row_start[hw + 1] - start;
  if (deg == 0) {
    *(f4*)&out[(size_t)hw * 128 + c4] = bb;
    return;
  }
  f4 hi = *(const f4*)&h[(size_t)hw * 128 + c4];
  int s_l = (lane < deg) ? src_csr[start + lane] : 0;
  int dcap = deg < 32 ? deg : 32;
  const f4* eap = (const f4*)&ea_csr[(size_t)start * 16];
  float m = -INFINITY, l = 0.f;
  f4 acc = (f4)0.f;
  for (int j = 0; j < deg; j++) {
    int s = (j < dcap) ? __shfl(s_l, j, 32) : src_csr[start + j];
    f4 hj = *(const f4*)&h[(size_t)s * 128 + c4];
    f4 v = hi + hj;
#pragma unroll
    for (int q = 0; q < 4; q++) {
      f4 aq = eap[(size_t)j * 4 + q];
      v += aq.x * W4[(4 * q + 0) * 32 + lane];
      v += aq.y * W4[(4 * q + 1) * 32 + lane];
      v += aq.z * W4[(4 * q + 2) * 32 + lane];
      v += aq.w * W4[(4 * q + 3) * 32 + lane];
    }
    v.x = v.x >= 0.f ? v.x : NEG * v.x;
    v.y = v.y >= 0.f ? v.y : NEG * v.y;
    v.z = v.z >= 0.f ? v.z : NEG * v.z;
    v.w = v.w >= 0.f ? v.w : NEG * v.w;
    f4 pv = v * attv;
    float sc = (pv.x + pv.y) + (pv.z + pv.w);
#pragma unroll
    for (int off = 16; off; off >>= 1) sc += __shfl_xor(sc, off);
    float mn = fmaxf(m, sc);
    float scale = __expf(m - mn);   // first edge: exp(-inf)=0
    float w = __expf(sc - mn);
    l = l * scale + w;
    acc = acc * scale + w * hj;
    m = mn;
  }
  float inv = 1.0f / (l + 1e-16f);
  f4 o = acc * inv + bb;
  *(f4*)&out[(size_t)hw * 128 + c4] = o;
}

// ---------------- layers 2+3 fused (wave/node, quarter-wave/edge, LDS weights) ----------------
__global__ __launch_bounds__(256) void fused23_kernel(
    const float* __restrict__ h3, const float* __restrict__ h2,
    const int* __restrict__ src_csr, const int* __restrict__ row_start,
    const float* __restrict__ ea_csr,
    const float* __restrict__ We3, const float* __restrict__ att3,
    const float* __restrict__ bias3, const float* __restrict__ We2,
    const float* __restrict__ att2, const float* __restrict__ bias2,
    float* __restrict__ out3, float* __restrict__ logits, int N) {
  __shared__ float We3S[512];
  __shared__ float att3S[32];
  __shared__ float We2S[16];
  int tid = threadIdx.x;
  for (int i = tid; i < 512; i += 256) We3S[i] = We3[i];
  if (tid < 32) att3S[tid] = att3[tid];
  if (tid < 16) We2S[tid] = We2[tid];
  __syncthreads();
  int wv = (blockIdx.x * 256 + tid) >> 6;
  int lane = tid & 63;
  if (wv >= N) return;
  int q4 = lane >> 4;        // quarter index 0..3
  int l16 = lane & 15;
  int c2 = l16 * 2;          // 2 dims per lane
  const f2* W3 = (const f2*)We3S;   // row k at W3[k*16 + l16]
  f2 at3 = *(const f2*)&att3S[c2];
  float a2s = att2[0];
  f2 bi3 = *(const f2*)&bias3[c2];
  int start = row_start[wv];
  int deg = row_start[wv + 1] - start;
  if (deg == 0) {
    if (lane < 16) *(f2*)&out3[(size_t)wv * 32 + c2] = bi3;
    if (lane == 0) logits[wv] = bias2[0];
    return;
  }
  f2 hi3 = *(const f2*)&h3[(size_t)wv * 32 + c2];
  float hi2 = h2[wv];
  int s_l = (lane < deg) ? src_csr[start + lane] : 0;
  int dcap = deg < 64 ? deg : 64;
  const float4* eap = (const float4*)&ea_csr[(size_t)start * 16];
  float m3 = -INFINITY, l3 = 0.f; f2 a3 = (f2)0.f;
  float m2 = -INFINITY, l2 = 0.f; float a2 = 0.f;
  for (int j = q4; j < deg; j += 4) {
    int s = (j < dcap) ? __shfl(s_l, j) : src_csr[start + j];
    f2 hj3 = *(const f2*)&h3[(size_t)s * 32 + c2];
    float h2s = h2[s];
    float4 c0 = eap[(size_t)j * 4 + 0];
    float4 c1 = eap[(size_t)j * 4 + 1];
    float4 cc2 = eap[(size_t)j * 4 + 2];
    float4 c3 = eap[(size_t)j * 4 + 3];
    f2 v = hi3 + hj3;
    v += c0.x * W3[0 * 16 + l16];  v += c0.y * W3[1 * 16 + l16];
    v += c0.z * W3[2 * 16 + l16];  v += c0.w * W3[3 * 16 + l16];
    v += c1.x * W3[4 * 16 + l16];  v += c1.y * W3[5 * 16 + l16];
    v += c1.z * W3[6 * 16 + l16];  v += c1.w * W3[7 * 16 + l16];
    v += cc2.x * W3[8 * 16 + l16]; v += cc2.y * W3[9 * 16 + l16];
    v += cc2.z * W3[10 * 16 + l16]; v += cc2.w * W3[11 * 16 + l16];
    v += c3.x * W3[12 * 16 + l16]; v += c3.y * W3[13 * 16 + l16];
    v += c3.z * W3[14 * 16 + l16]; v += c3.w * W3[15 * 16 + l16];
    v.x = v.x >= 0.f ? v.x : NEG * v.x;
    v.y = v.y >= 0.f ? v.y : NEG * v.y;
    float t3 = v.x * at3.x + v.y * at3.y;
#pragma unroll
    for (int off = 8; off; off >>= 1) t3 += __shfl_xor(t3, off);
    float v2 = hi2 + h2s;
    v2 += c0.x * We2S[0]  + c0.y * We2S[1]  + c0.z * We2S[2]  + c0.w * We2S[3];
    v2 += c1.x * We2S[4]  + c1.y * We2S[5]  + c1.z * We2S[6]  + c1.w * We2S[7];
    v2 += cc2.x * We2S[8] + cc2.y * We2S[9] + cc2.z * We2S[10] + cc2.w * We2S[11];
    v2 += c3.x * We2S[12] + c3.y * We2S[13] + c3.z * We2S[14] + c3.w * We2S[15];
    v2 = v2 >= 0.f ? v2 : NEG * v2;
    float t2 = v2 * a2s;
    float mn3 = fmaxf(m3, t3);
    float sc3 = __expf(m3 - mn3);
    float w3 = __expf(t3 - mn3);
    l3 = l3 * sc3 + w3;
    a3 = a3 * sc3 + w3 * hj3;
    m3 = mn3;
    float mn2 = fmaxf(m2, t2);
    float sc2 = __expf(m2 - mn2);
    float w2 = __expf(t2 - mn2);
    l2 = l2 * sc2 + w2;
    a2 = a2 * sc2 + w2 * h2s;
    m2 = mn2;
  }
  // merge 4 quarter states (xor 16 then 32); quarter 0 has >=1 edge
#pragma unroll
  for (int off = 16; off <= 32; off <<= 1) {
    float m3o = __shfl_xor(m3, off), l3o = __shfl_xor(l3, off);
    float ax = __shfl_xor(a3.x, off), ay = __shfl_xor(a3.y, off);
    float M3 = fmaxf(m3, m3o);
    float sA = (m3 == -INFINITY) ? 0.f : __expf(m3 - M3);
    float sB = (m3o == -INFINITY) ? 0.f : __expf(m3o - M3);
    l3 = l3 * sA + l3o * sB;
    a3.x = a3.x * sA + ax * sB;
    a3.y = a3.y * sA + ay * sB;
    m3 = M3;
    float m2o = __shfl_xor(m2, off), l2o = __shfl_xor(l2, off);
    float az = __shfl_xor(a2, off);
    float M2 = fmaxf(m2, m2o);
    float tA = (m2 == -INFINITY) ? 0.f : __expf(m2 - M2);
    float tB = (m2o == -INFINITY) ? 0.f : __expf(m2o - M2);
    l2 = l2 * tA + l2o * tB;
    a2 = a2 * tA + az * tB;
    m2 = M2;
  }
  if (lane < 16) {
    f2 o;
    o.x = a3.x / (l3 + 1e-16f) + bi3.x;
    o.y = a3.y / (l3 + 1e-16f) + bi3.y;
    *(f2*)&out3[(size_t)wv * 32 + c2] = o;
  }
  if (lane == 0) logits[wv] = a2 / (l2 + 1e-16f) + bias2[0];
}

// ---------------- node categorical: 64-block partial + 1-wave final ----------------
#define NSB 64
__global__ __launch_bounds__(256) void node_partial_kernel(const float* __restrict__ logits,
    int N, uint32_t ka, uint32_t kb,
    float* __restrict__ pB, int* __restrict__ pI,
    float* __restrict__ pM, float* __restrict__ pL) {
  int chunk = (N + NSB - 1) / NSB;
  int s0 = blockIdx.x * chunk;
  int s1 = s0 + chunk; if (s1 > N) s1 = N;
  int tid = threadIdx.x;
  float best = -INFINITY; int bi = 0x7fffffff;
  float m = -INFINITY, l = 0.f;
  for (int i = s0 + tid; i < s1; i += 256) {
    float lg = logits[i];
    float mn = fmaxf(m, lg);
    l = l * __expf(m - mn) + __expf(lg - mn);
    m = mn;
    float v = lg + gumbel_part(ka, kb, (uint32_t)i);
    if (v > best) { best = v; bi = i; }
  }
  __shared__ float sb[256], sm[256], sl[256];
  __shared__ int si[256];
  sb[tid] = best; si[tid] = bi; sm[tid] = m; sl[tid] = l;
  __syncthreads();
  for (int s = 128; s; s >>= 1) {
    if (tid < s) {
      if (sb[tid + s] > sb[tid] || (sb[tid + s] == sb[tid] && si[tid + s] < si[tid])) {
        sb[tid] = sb[tid + s]; si[tid] = si[tid + s];
      }
      float M = fmaxf(sm[tid], sm[tid + s]);
      float t0 = (sm[tid] == -INFINITY) ? 0.f : sl[tid] * __expf(sm[tid] - M);
      float t1 = (sm[tid + s] == -INFINITY) ? 0.f : sl[tid + s] * __expf(sm[tid + s] - M);
      sm[tid] = M; sl[tid] = t0 + t1;
    }
    __syncthreads();
  }
  if (tid == 0) { pB[blockIdx.x] = sb[0]; pI[blockIdx.x] = si[0]; pM[blockIdx.x] = sm[0]; pL[blockIdx.x] = sl[0]; }
}

__global__ __launch_bounds__(64) void node_final_kernel(const float* __restrict__ logits,
    const float* __restrict__ pB, const int* __restrict__ pI,
    const float* __restrict__ pM, const float* __restrict__ pL,
    float* __restrict__ scal) {
  int lane = threadIdx.x;
  float best = pB[lane]; int bi = pI[lane];
  float m = pM[lane]; float l = pL[lane];
#pragma unroll
  for (int off = 32; off; off >>= 1) {
    float ob = __shfl_xor(best, off); int oi = __shfl_xor(bi, off);
    if (ob > best || (ob == best && oi < bi)) { best = ob; bi = oi; }
    float om = __shfl_xor(m, off); float ol = __shfl_xor(l, off);
    float M = fmaxf(m, om);
    float t0 = (m == -INFINITY) ? 0.f : l * __expf(m - M);
    float t1 = (om == -INFINITY) ? 0.f : ol * __expf(om - M);
    m = M; l = t0 + t1;
  }
  if (lane == 0) {
    ((int*)scal)[0] = bi;
    scal[3] = logits[bi] - (m + logf(l));
  }
}

// ---------------- action categorical + output ----------------
__global__ __launch_bounds__(64) void action_kernel(const float* __restrict__ out3,
    const float* __restrict__ scal, uint32_t ka, uint32_t kb,
    float* __restrict__ dout, int out_size) {
  int lane = threadIdx.x;
  int sel = ((const int*)scal)[0];
  float v = -INFINITY, noisy = -INFINITY;
  if (lane < 32) {
    v = out3[(size_t)sel * 32 + lane];
    noisy = v + gumbel_part(ka, kb, (uint32_t)lane);
  }
  int idx = lane;
  float nv = noisy;
#pragma unroll
  for (int off = 32; off; off >>= 1) {
    float ov = __shfl_xor(nv, off);
    int oi = __shfl_xor(idx, off);
    if (ov > nv || (ov == nv && oi < idx)) { nv = ov; idx = oi; }
  }
  float vm = v;
#pragma unroll
  for (int off = 32; off; off >>= 1) vm = fmaxf(vm, __shfl_xor(vm, off));
  float ex = (lane < 32) ? expf(v - vm) : 0.f;
#pragma unroll
  for (int off = 32; off; off >>= 1) ex += __shfl_xor(ex, off);
  float vsel = __shfl(v, idx);
  if (lane == 0) {
    float action_lp = vsel - vm - logf(ex);
    dout[0] = (float)sel;
    dout[1] = (float)idx;
    dout[2] = scal[3] + action_lp;
  }
  for (int i = 3 + lane; i < out_size; i += 64) dout[i] = 0.f;
}

extern "C" void kernel_launch(void* const* d_in, const int* in_sizes, int n_in,
                              void* d_out, int out_size, void* d_ws, size_t ws_size,
                              hipStream_t stream) {
  const float* x     = (const float*)d_in[0];
  const int*   ei    = (const int*)d_in[1];
  const float* ea    = (const float*)d_in[2];
  const float* Wl1   = (const float*)d_in[3];
  const float* bl1   = (const float*)d_in[4];
  const float* We1   = (const float*)d_in[5];
  const float* att1  = (const float*)d_in[6];
  const float* bias1 = (const float*)d_in[7];
  const float* Wl2   = (const float*)d_in[8];
  const float* bl2   = (const float*)d_in[9];
  const float* We2   = (const float*)d_in[10];
  const float* att2  = (const float*)d_in[11];
  const float* bias2 = (const float*)d_in[12];
  const float* Wl3   = (const float*)d_in[13];
  const float* bl3   = (const float*)d_in[14];
  const float* We3   = (const float*)d_in[15];
  const float* att3  = (const float*)d_in[16];
  const float* bias3 = (const float*)d_in[17];
  int N = in_sizes[0] / 128;
  int E = in_sizes[1] / 2;
  float* out = (float*)d_out;

  char* p = (char*)d_ws;
  auto alloc = [&](size_t bytes) -> char* {
    char* r = p; p += (bytes + 255) & ~(size_t)255; return r;
  };
  float* h1      = (float*)alloc((size_t)N * 128 * 4);
  float* latent  = (float*)alloc((size_t)N * 128 * 4);
  float* h3      = (float*)alloc((size_t)N * 32 * 4);
  float* h2      = (float*)alloc((size_t)N * 4);
  float* logits  = (float*)alloc((size_t)N * 4);
  float* out3    = (float*)alloc((size_t)N * 32 * 4);
  int* counts    = (int*)alloc((size_t)N * 4);
  int* row_start = (int*)alloc((size_t)(N + 1) * 4);
  int* cursor    = (int*)alloc((size_t)N * 4);
  int* src_csr   = (int*)alloc((size_t)E * 4);
  float* ea_csr  = (float*)alloc((size_t)E * 16 * 4);
  int* bsum      = (int*)alloc(SCB * 4);
  int* boff      = (int*)alloc(SCB * 4);
  float* pB      = (float*)alloc(NSB * 4);
  int*   pI      = (int*)alloc(NSB * 4);
  float* pM      = (float*)alloc(NSB * 4);
  float* pL      = (float*)alloc(NSB * 4);
  float* scal    = (float*)alloc(64);
  (void)ws_size; (void)n_in;

  // JAX PRNG (partitionable): key(42)=(0,42); subkey_i = TF(key,(0,i))
  uint32_t k1a, k1b, k2a, k2b;
  threefry2x32(0u, 42u, 0u, 0u, &k1a, &k1b);
  threefry2x32(0u, 42u, 0u, 1u, &k2a, &k2b);

  int chunk = (N + SCB - 1) / SCB;

  hipMemsetAsync(counts, 0, (size_t)N * 4, stream);
  count_kernel<<<(E + 255) / 256, 256, 0, stream>>>(ei, E, counts);
  scan_partial_kernel<<<SCB, 256, 0, stream>>>(counts, N, chunk, bsum);
  scan_offsets_kernel<<<1, 256, 0, stream>>>(bsum, boff, row_start, N);
  scan_apply_kernel<<<SCB, 256, 0, stream>>>(counts, boff, N, chunk, row_start, cursor);
  scatter_kernel<<<(E + 255) / 256, 256, 0, stream>>>(ei, ea, E, cursor, src_csr, ea_csr);

  gemm128_kernel<<<(N + 31) / 32, 256, 0, stream>>>(x, Wl1, bl1, h1, N);
  fused1_kernel<<<(N + 7) / 8, 256, 0, stream>>>(h1, src_csr, row_start,
                                                 ea_csr, We1, att1, bias1, latent, N);

  gemm32_kernel<<<((size_t)N * 32 + 255) / 256, 256, 0, stream>>>(latent, Wl3, bl3, h3, N);
  gemv_kernel<<<(N + 3) / 4, 256, 0, stream>>>(latent, Wl2, bl2, h2, N);

  fused23_kernel<<<(N + 3) / 4, 256, 0, stream>>>(h3, h2, src_csr, row_start, ea_csr,
                                                  We3, att3, bias3, We2, att2, bias2,
                                                  out3, logits, N);

  node_partial_kernel<<<NSB, 256, 0, stream>>>(logits, N, k1a, k1b, pB, pI, pM, pL);
  node_final_kernel<<<1, 64, 0, stream>>>(logits, pB, pI, pM, pL, scal);
  action_kernel<<<1, 64, 0, stream>>>(out3, scal, k2a, k2b, out, out_size);
}